// Round 1
// baseline (1592.710 us; speedup 1.0000x reference)
//
#include <hip/hip_runtime.h>

#define GN 256
#define NPG 360
#define NN (GN*NPG)      // 92160
#define DEGAVG 16
#define EE (NN*DEGAVG)   // 1474560
#define HH 5
#define CC 30
#define IN_CH 11
#define NUM_GC 9
#define EPS 1e-5f

__device__ __forceinline__ float wred_sum(float v) {
#pragma unroll
  for (int m = 32; m >= 1; m >>= 1) v += __shfl_xor(v, m);
  return v;
}
__device__ __forceinline__ float wred_max(float v) {
#pragma unroll
  for (int m = 32; m >= 1; m >>= 1) v = fmaxf(v, __shfl_xor(v, m));
  return v;
}

// ---------- CSR build ----------
__global__ void k_hist(const int* __restrict__ dst, int* __restrict__ deg) {
  int e = blockIdx.x * blockDim.x + threadIdx.x;
  if (e < EE) atomicAdd(&deg[dst[e]], 1);
}

__global__ __launch_bounds__(1024) void k_scan(const int* __restrict__ deg, int* __restrict__ rowp) {
  __shared__ int sums[1024];
  int tid = threadIdx.x;
  const int chunk = (NN + 1023) / 1024;   // 90
  int start = tid * chunk;
  int end = min(start + chunk, NN);
  int s = 0;
  for (int i = start; i < end; i++) s += deg[i];
  sums[tid] = s;
  __syncthreads();
  for (int off = 1; off < 1024; off <<= 1) {
    int v = (tid >= off) ? sums[tid - off] : 0;
    __syncthreads();
    sums[tid] += v;
    __syncthreads();
  }
  int run = (tid == 0) ? 0 : sums[tid - 1];
  for (int i = start; i < end; i++) { rowp[i] = run; run += deg[i]; }
  if (tid == 1023) rowp[NN] = sums[1023];
}

__global__ void k_scatter(const int* __restrict__ src, const int* __restrict__ dst,
                          const int* __restrict__ rowp, int* __restrict__ cursor,
                          int* __restrict__ eidx, int* __restrict__ srcs) {
  int e = blockIdx.x * blockDim.x + threadIdx.x;
  if (e >= EE) return;
  int d = dst[e];
  int pos = rowp[d] + atomicAdd(&cursor[d], 1);
  eidx[pos] = e;
  srcs[pos] = src[e];
}

// ---------- EGAT: xp = einsum(x, egat_w); per-node attention dot products ----------
__global__ void k_xp(const float* __restrict__ x, const float* __restrict__ egw,
                     const float* __restrict__ att_s, const float* __restrict__ att_d,
                     float* __restrict__ xp, float* __restrict__ ssrc, float* __restrict__ sdst) {
  int t = blockIdx.x * blockDim.x + threadIdx.x;
  if (t >= NN * HH) return;
  int n = t / HH, h = t % HH;
  float xi[IN_CH];
#pragma unroll
  for (int i = 0; i < IN_CH; i++) xi[i] = x[n * IN_CH + i];
  float s1 = 0.f, s2 = 0.f;
#pragma unroll
  for (int c = 0; c < CC; c++) {
    float v = 0.f;
#pragma unroll
    for (int i = 0; i < IN_CH; i++) v += xi[i] * egw[(i * HH + h) * CC + c];
    xp[(n * HH + h) * CC + c] = v;
    s1 += v * att_s[h * CC + c];
    s2 += v * att_d[h * CC + c];
  }
  ssrc[t] = s1;
  sdst[t] = s2;
}

// ---------- EGAT per-node softmax + aggregation (one wave per node) ----------
__global__ __launch_bounds__(64) void k_egat(
    const int* __restrict__ rowp, const int* __restrict__ srcs, const int* __restrict__ eidx,
    const float* __restrict__ eattr, const float* __restrict__ ssrc, const float* __restrict__ sdst,
    const float* __restrict__ att_e, const float* __restrict__ xp,
    float* __restrict__ ew, float* __restrict__ hout) {
  int n = blockIdx.x;
  int lane = threadIdx.x;
  int beg = rowp[n], end = rowp[n + 1];
  int deg = end - beg;
  if (deg == 0) {
    if (lane < CC) hout[n * CC + lane] = 0.f;
    return;
  }
  float sd[HH], ae[HH];
#pragma unroll
  for (int h = 0; h < HH; h++) { sd[h] = sdst[n * HH + h]; ae[h] = att_e[h]; }

  // pass 1: per-head max over incoming edges
  float mx[HH];
#pragma unroll
  for (int h = 0; h < HH; h++) mx[h] = -1e30f;
  for (int p = beg + lane; p < end; p += 64) {
    int s = srcs[p];
    float ea = eattr[eidx[p]];
#pragma unroll
    for (int h = 0; h < HH; h++) {
      float l = ssrc[s * HH + h] + sd[h] + ea * ae[h];
      l = l > 0.f ? l : 0.2f * l;
      mx[h] = fmaxf(mx[h], l);
    }
  }
#pragma unroll
  for (int h = 0; h < HH; h++) mx[h] = wred_max(mx[h]);

  // pass 2: per-head denom
  float dn[HH];
#pragma unroll
  for (int h = 0; h < HH; h++) dn[h] = 0.f;
  for (int p = beg + lane; p < end; p += 64) {
    int s = srcs[p];
    float ea = eattr[eidx[p]];
#pragma unroll
    for (int h = 0; h < HH; h++) {
      float l = ssrc[s * HH + h] + sd[h] + ea * ae[h];
      l = l > 0.f ? l : 0.2f * l;
      dn[h] += __expf(l - mx[h]);
    }
  }
#pragma unroll
  for (int h = 0; h < HH; h++) { dn[h] = wred_sum(dn[h]); dn[h] += 1e-16f; }

  // pass 3: alpha, ew, aggregate h = mean_h sum_e alpha*xp[src]
  __shared__ float al_s[64][HH];
  __shared__ int src_s[64];
  float acc = 0.f;
  for (int cb = beg; cb < end; cb += 64) {
    int csz = min(64, end - cb);
    if (lane < csz) {
      int p = cb + lane;
      int s = srcs[p];
      src_s[lane] = s;
      float ea = eattr[eidx[p]];
      float ews = 0.f;
#pragma unroll
      for (int h = 0; h < HH; h++) {
        float l = ssrc[s * HH + h] + sd[h] + ea * ae[h];
        l = l > 0.f ? l : 0.2f * l;
        float a = __expf(l - mx[h]) / dn[h];
        al_s[lane][h] = a;
        ews += a;
      }
      ew[p] = ews * 0.2f;   // mean over 5 heads
    }
    __syncthreads();
    if (lane < CC) {
      for (int e2 = 0; e2 < csz; e2++) {
        const float* xb = xp + (size_t)src_s[e2] * (HH * CC) + lane;
        float a = 0.f;
#pragma unroll
        for (int h = 0; h < HH; h++) a += al_s[e2][h] * xb[h * CC];
        acc += a;
      }
    }
    __syncthreads();
  }
  if (lane < CC) hout[n * CC + lane] = acc * 0.2f;  // mean over heads
}

// ---------- per-node 30x30 matmul: out = h @ W ----------
__global__ void k_matmul30(const float* __restrict__ hin, const float* __restrict__ W,
                           float* __restrict__ out) {
  int t = blockIdx.x * blockDim.x + threadIdx.x;
  if (t >= NN * CC) return;
  int n = t / CC, c = t % CC;
  const float* hr = hin + (size_t)n * CC;
  float acc = 0.f;
#pragma unroll
  for (int k = 0; k < CC; k++) acc += hr[k] * W[k * CC + c];
  out[t] = acc;
}

// ---------- GraphConv: h = h@Wroot + sum_e ew*hw[src] + b (in place) ----------
__global__ __launch_bounds__(64) void k_gc(const int* __restrict__ rowp, const int* __restrict__ srcs,
                                           const float* __restrict__ ew, const float* __restrict__ hw,
                                           const float* __restrict__ Wroot, const float* __restrict__ bias,
                                           float* __restrict__ h) {
  int n = blockIdx.x, lane = threadIdx.x;
  __shared__ float hrow[CC];
  __shared__ float ew_s[64];
  __shared__ int src_s[64];
  if (lane < CC) hrow[lane] = h[(size_t)n * CC + lane];
  __syncthreads();
  float root = 0.f;
  if (lane < CC) {
#pragma unroll
    for (int k = 0; k < CC; k++) root += hrow[k] * Wroot[k * CC + lane];
  }
  int beg = rowp[n], end = rowp[n + 1];
  float msg = 0.f;
  for (int cb = beg; cb < end; cb += 64) {
    int csz = min(64, end - cb);
    if (lane < csz) { ew_s[lane] = ew[cb + lane]; src_s[lane] = srcs[cb + lane]; }
    __syncthreads();
    if (lane < CC) {
      for (int e2 = 0; e2 < csz; e2++) msg += ew_s[e2] * hw[(size_t)src_s[e2] * CC + lane];
    }
    __syncthreads();
  }
  if (lane < CC) h[(size_t)n * CC + lane] = root + msg + bias[lane];
}

// ---------- InstanceNorm (in place) + per-graph max pool ----------
__global__ __launch_bounds__(64) void k_norm_pool(float* __restrict__ h, float* __restrict__ pooled,
                                                  int layer) {
  int g = blockIdx.x / CC, c = blockIdx.x % CC;
  int lane = threadIdx.x;
  float s = 0.f, s2 = 0.f;
  for (int i = lane; i < NPG; i += 64) {
    float v = h[((size_t)g * NPG + i) * CC + c];
    s += v; s2 += v * v;
  }
  s = wred_sum(s); s2 = wred_sum(s2);
  float mean = s / (float)NPG;
  float var = s2 / (float)NPG - mean * mean;
  float rs = rsqrtf(var + EPS);
  float mx = -1e30f;
  for (int i = lane; i < NPG; i += 64) {
    size_t idx = ((size_t)g * NPG + i) * CC + c;
    float v = (h[idx] - mean) * rs;
    h[idx] = v;
    mx = fmaxf(mx, v);
  }
  mx = wred_max(mx);
  if (lane == 0) pooled[(size_t)g * (10 * CC) + layer * CC + c] = mx;
}

// ---------- final MLP ----------
__global__ __launch_bounds__(64) void k_fc(const float* __restrict__ pooled,
                                           const float* __restrict__ fc1w, const float* __restrict__ fc1b,
                                           const float* __restrict__ fc2w, const float* __restrict__ fc2b,
                                           float* __restrict__ out) {
  int g = blockIdx.x, lane = threadIdx.x;
  __shared__ float hid[50];
  if (lane < 50) {
    float acc = fc1b[lane];
    const float* pr = pooled + (size_t)g * 300;
    for (int i = 0; i < 300; i++) acc += pr[i] * fc1w[i * 50 + lane];
    hid[lane] = acc > 0.f ? acc : 0.f;
  }
  __syncthreads();
  if (lane < 2) {
    float o = fc2b[lane];
#pragma unroll
    for (int j = 0; j < 50; j++) o += hid[j] * fc2w[j * 2 + lane];
    out[(size_t)g * 2 + lane] = o;
  }
}

extern "C" void kernel_launch(void* const* d_in, const int* in_sizes, int n_in,
                              void* d_out, int out_size, void* d_ws, size_t ws_size,
                              hipStream_t stream) {
  const float* x     = (const float*)d_in[0];
  const int*   ei    = (const int*)d_in[1];
  const int*   esrc  = ei;
  const int*   edst  = ei + EE;
  const float* eattr = (const float*)d_in[2];
  const float* egw   = (const float*)d_in[4];
  const float* att_s = (const float*)d_in[5];
  const float* att_d = (const float*)d_in[6];
  const float* att_e = (const float*)d_in[7];
  const float* wroot = (const float*)d_in[8];
  const float* wnbr  = (const float*)d_in[9];
  const float* gcb   = (const float*)d_in[10];
  const float* fc1w  = (const float*)d_in[11];
  const float* fc1b  = (const float*)d_in[12];
  const float* fc2w  = (const float*)d_in[13];
  const float* fc2b  = (const float*)d_in[14];
  float* out = (float*)d_out;

  char* ws = (char*)d_ws;
  size_t off = 0;
  auto alloc = [&](size_t bytes) -> void* {
    void* p = ws + off;
    off += (bytes + 255) & ~(size_t)255;
    return p;
  };
  float* xp     = (float*)alloc((size_t)NN * HH * CC * 4);
  float* ssrc   = (float*)alloc((size_t)NN * HH * 4);
  float* sdst   = (float*)alloc((size_t)NN * HH * 4);
  float* h      = (float*)alloc((size_t)NN * CC * 4);
  float* hw     = (float*)alloc((size_t)NN * CC * 4);
  float* ew     = (float*)alloc((size_t)EE * 4);
  float* pooled = (float*)alloc((size_t)GN * 300 * 4);
  int*   deg    = (int*)alloc((size_t)NN * 4);
  int*   rowp   = (int*)alloc((size_t)(NN + 1) * 4);
  int*   cursor = (int*)alloc((size_t)NN * 4);
  int*   eidx   = (int*)alloc((size_t)EE * 4);
  int*   srcs   = (int*)alloc((size_t)EE * 4);

  // CSR build
  hipMemsetAsync(deg, 0, (size_t)NN * 4, stream);
  k_hist<<<(EE + 255) / 256, 256, 0, stream>>>(edst, deg);
  k_scan<<<1, 1024, 0, stream>>>(deg, rowp);
  hipMemsetAsync(cursor, 0, (size_t)NN * 4, stream);
  k_scatter<<<(EE + 255) / 256, 256, 0, stream>>>(esrc, edst, rowp, cursor, eidx, srcs);

  // EGAT
  k_xp<<<(NN * HH + 255) / 256, 256, 0, stream>>>(x, egw, att_s, att_d, xp, ssrc, sdst);
  k_egat<<<NN, 64, 0, stream>>>(rowp, srcs, eidx, eattr, ssrc, sdst, att_e, xp, ew, h);
  k_norm_pool<<<GN * CC, 64, 0, stream>>>(h, pooled, 0);

  // 9 GraphConv layers
  for (int l = 0; l < NUM_GC; l++) {
    k_matmul30<<<(NN * CC + 255) / 256, 256, 0, stream>>>(h, wnbr + (size_t)l * CC * CC, hw);
    k_gc<<<NN, 64, 0, stream>>>(rowp, srcs, ew, hw, wroot + (size_t)l * CC * CC, gcb + (size_t)l * CC, h);
    k_norm_pool<<<GN * CC, 64, 0, stream>>>(h, pooled, l + 1);
  }

  // final MLP
  k_fc<<<GN, 64, 0, stream>>>(pooled, fc1w, fc1b, fc2w, fc2b, out);
}

// Round 2
// 509.050 us; speedup vs baseline: 3.1288x; 3.1288x over previous
//
#include <hip/hip_runtime.h>

#define GN 256
#define NPG 360
#define NN (GN*NPG)      // 92160
#define DEGAVG 16
#define EE (NN*DEGAVG)   // 1474560
#define EPG (NPG*DEGAVG) // 5760 edges per graph
#define HH 5
#define CC 30
#define IN_CH 11
#define NUM_GC 9
#define EPS 1e-5f
#define HP 36            // padded LDS row stride (floats): 16B-aligned, bank-spread

__device__ __forceinline__ float wred_sum(float v) {
#pragma unroll
  for (int m = 32; m >= 1; m >>= 1) v += __shfl_xor(v, m);
  return v;
}
__device__ __forceinline__ float wred_max(float v) {
#pragma unroll
  for (int m = 32; m >= 1; m >>= 1) v = fmaxf(v, __shfl_xor(v, m));
  return v;
}

// ---------- CSR build ----------
__global__ void k_hist(const int* __restrict__ dst, int* __restrict__ deg) {
  int e = blockIdx.x * blockDim.x + threadIdx.x;
  if (e < EE) atomicAdd(&deg[dst[e]], 1);
}

__global__ __launch_bounds__(1024) void k_scan(const int* __restrict__ deg, int* __restrict__ rowp) {
  __shared__ int sums[1024];
  int tid = threadIdx.x;
  const int chunk = (NN + 1023) / 1024;   // 90
  int start = tid * chunk;
  int end = min(start + chunk, NN);
  int s = 0;
  for (int i = start; i < end; i++) s += deg[i];
  sums[tid] = s;
  __syncthreads();
  for (int off = 1; off < 1024; off <<= 1) {
    int v = (tid >= off) ? sums[tid - off] : 0;
    __syncthreads();
    sums[tid] += v;
    __syncthreads();
  }
  int run = (tid == 0) ? 0 : sums[tid - 1];
  for (int i = start; i < end; i++) { rowp[i] = run; run += deg[i]; }
  if (tid == 1023) rowp[NN] = sums[1023];
}

__global__ void k_scatter(const int* __restrict__ src, const int* __restrict__ dst,
                          const float* __restrict__ eattr,
                          const int* __restrict__ rowp, int* __restrict__ cursor,
                          int* __restrict__ srcs, float* __restrict__ eattr_p) {
  int e = blockIdx.x * blockDim.x + threadIdx.x;
  if (e >= EE) return;
  int d = dst[e];
  int pos = rowp[d] + atomicAdd(&cursor[d], 1);
  srcs[pos] = src[e];
  eattr_p[pos] = eattr[e];
}

// ---------- EGAT: xp = einsum(x, egat_w); per-node attention dot products ----------
__global__ void k_xp(const float* __restrict__ x, const float* __restrict__ egw,
                     const float* __restrict__ att_s, const float* __restrict__ att_d,
                     float* __restrict__ xp, float* __restrict__ ssrc, float* __restrict__ sdst) {
  int t = blockIdx.x * blockDim.x + threadIdx.x;
  if (t >= NN * HH) return;
  int n = t / HH, h = t - n * HH;
  float xi[IN_CH];
#pragma unroll
  for (int i = 0; i < IN_CH; i++) xi[i] = x[n * IN_CH + i];
  float s1 = 0.f, s2 = 0.f;
#pragma unroll
  for (int c = 0; c < CC; c++) {
    float v = 0.f;
#pragma unroll
    for (int i = 0; i < IN_CH; i++) v += xi[i] * egw[(i * HH + h) * CC + c];
    xp[((size_t)n * HH + h) * CC + c] = v;
    s1 += v * att_s[h * CC + c];
    s2 += v * att_d[h * CC + c];
  }
  ssrc[n * 8 + h] = s1;
  sdst[n * 8 + h] = s2;
}

// ---------- EGAT per-node softmax + aggregation (one wave per node) ----------
__global__ __launch_bounds__(64) void k_egat(
    const int* __restrict__ rowp, const int* __restrict__ srcs,
    const float* __restrict__ eattr_p,
    const float* __restrict__ ssrc, const float* __restrict__ sdst,
    const float* __restrict__ att_e, const float* __restrict__ xp,
    float* __restrict__ ew, float* __restrict__ hout) {
  __shared__ float al_s[64][HH];
  __shared__ int src_s[64];
  int nn = blockIdx.x;
  int lane = threadIdx.x;
  int beg = rowp[nn], end = rowp[nn + 1];
  int deg = end - beg;
  if (deg == 0) {
    if (lane < CC) hout[(size_t)nn * CC + lane] = 0.f;
    return;
  }
  float sd[HH], ae[HH];
#pragma unroll
  for (int h = 0; h < HH; h++) { sd[h] = sdst[nn * 8 + h]; ae[h] = att_e[h]; }

  if (deg <= 64) {
    // ---- fast path: one lane per edge, logits computed exactly once ----
    float lg[HH];
    int s = 0;
    if (lane < deg) {
      int p = beg + lane;
      s = srcs[p];
      float ea = eattr_p[p];
#pragma unroll
      for (int h = 0; h < HH; h++) {
        float t = ssrc[s * 8 + h] + sd[h] + ea * ae[h];
        lg[h] = t > 0.f ? t : 0.2f * t;
      }
    } else {
#pragma unroll
      for (int h = 0; h < HH; h++) lg[h] = -1e30f;
    }
    float ex[HH], dn[HH];
#pragma unroll
    for (int h = 0; h < HH; h++) {
      float mx = wred_max(lg[h]);
      ex[h] = (lane < deg) ? __expf(lg[h] - mx) : 0.f;
      dn[h] = wred_sum(ex[h]) + 1e-16f;
    }
    if (lane < deg) {
      src_s[lane] = s;
      float ews = 0.f;
#pragma unroll
      for (int h = 0; h < HH; h++) {
        float a = ex[h] / dn[h];
        al_s[lane][h] = a;
        ews += a;
      }
      ew[beg + lane] = ews * 0.2f;
    }
    __syncthreads();
    // aggregation: both wave halves split the edge loop
    float a0 = 0.f;
    int c = lane & 31, half = lane >> 5;
    if (c < CC) {
      for (int e2 = half; e2 < deg; e2 += 2) {
        const float* xb = xp + (size_t)src_s[e2] * (HH * CC) + c;
        float a = 0.f;
#pragma unroll
        for (int h = 0; h < HH; h++) a += al_s[e2][h] * xb[h * CC];
        a0 += a;
      }
    }
    a0 += __shfl_xor(a0, 32);
    if (lane < CC) hout[(size_t)nn * CC + lane] = a0 * 0.2f;
    return;
  }

  // ---- slow path (deg > 64): 3-pass chunked (statistically never taken) ----
  float mx[HH];
#pragma unroll
  for (int h = 0; h < HH; h++) mx[h] = -1e30f;
  for (int p = beg + lane; p < end; p += 64) {
    int s = srcs[p];
    float ea = eattr_p[p];
#pragma unroll
    for (int h = 0; h < HH; h++) {
      float l = ssrc[s * 8 + h] + sd[h] + ea * ae[h];
      l = l > 0.f ? l : 0.2f * l;
      mx[h] = fmaxf(mx[h], l);
    }
  }
#pragma unroll
  for (int h = 0; h < HH; h++) mx[h] = wred_max(mx[h]);
  float dn[HH];
#pragma unroll
  for (int h = 0; h < HH; h++) dn[h] = 0.f;
  for (int p = beg + lane; p < end; p += 64) {
    int s = srcs[p];
    float ea = eattr_p[p];
#pragma unroll
    for (int h = 0; h < HH; h++) {
      float l = ssrc[s * 8 + h] + sd[h] + ea * ae[h];
      l = l > 0.f ? l : 0.2f * l;
      dn[h] += __expf(l - mx[h]);
    }
  }
#pragma unroll
  for (int h = 0; h < HH; h++) { dn[h] = wred_sum(dn[h]); dn[h] += 1e-16f; }
  float acc = 0.f;
  for (int cb = beg; cb < end; cb += 64) {
    int csz = min(64, end - cb);
    if (lane < csz) {
      int p = cb + lane;
      int s = srcs[p];
      src_s[lane] = s;
      float ea = eattr_p[p];
      float ews = 0.f;
#pragma unroll
      for (int h = 0; h < HH; h++) {
        float l = ssrc[s * 8 + h] + sd[h] + ea * ae[h];
        l = l > 0.f ? l : 0.2f * l;
        float a = __expf(l - mx[h]) / dn[h];
        al_s[lane][h] = a;
        ews += a;
      }
      ew[p] = ews * 0.2f;
    }
    __syncthreads();
    if (lane < CC) {
      for (int e2 = 0; e2 < csz; e2++) {
        const float* xb = xp + (size_t)src_s[e2] * (HH * CC) + lane;
        float a = 0.f;
#pragma unroll
        for (int h = 0; h < HH; h++) a += al_s[e2][h] * xb[h * CC];
        acc += a;
      }
    }
    __syncthreads();
  }
  if (lane < CC) hout[(size_t)nn * CC + lane] = acc * 0.2f;
}

// ---------- InstanceNorm (in LDS) + per-graph max pool ----------
__device__ __forceinline__ void norm_pool(float* h_l, float* pooled_l, int layer, int tid) {
  if (tid < 480) {
    int c = tid >> 4, j = tid & 15;   // 16 lanes per channel (lane-aligned groups)
    float s = 0.f, s2 = 0.f;
    for (int i = j; i < NPG; i += 16) {
      float v = h_l[i * HP + c];
      s += v; s2 += v * v;
    }
#pragma unroll
    for (int m = 8; m >= 1; m >>= 1) { s += __shfl_xor(s, m); s2 += __shfl_xor(s2, m); }
    float mean = s * (1.f / NPG);
    float var = s2 * (1.f / NPG) - mean * mean;
    float rs = rsqrtf(var + EPS);
    float mx = -1e30f;
    for (int i = j; i < NPG; i += 16) {
      float v = (h_l[i * HP + c] - mean) * rs;
      h_l[i * HP + c] = v;
      mx = fmaxf(mx, v);
    }
#pragma unroll
    for (int m = 8; m >= 1; m >>= 1) mx = fmaxf(mx, __shfl_xor(mx, m));
    if (j == 0) pooled_l[layer * CC + c] = mx;
  }
}

// ---------- mega-kernel: 9 x (GraphConv + InstanceNorm) + pool + MLP, one graph per block ----------
__global__ __launch_bounds__(512) void k_gcall(
    const int* __restrict__ rowp, const int* __restrict__ srcs,
    const float* __restrict__ ew, const float* __restrict__ h_in,
    const float* __restrict__ wnbr, const float* __restrict__ wroot,
    const float* __restrict__ gcb,
    const float* __restrict__ fc1w, const float* __restrict__ fc1b,
    const float* __restrict__ fc2w, const float* __restrict__ fc2b,
    float* __restrict__ out) {
  __shared__ float h_l[NPG * HP];          // 51.84 KB
  __shared__ float hw_l[NPG * HP];         // 51.84 KB
  __shared__ float ew_l[EPG];              // 23.04 KB
  __shared__ unsigned short srcs_l[EPG];   // 11.52 KB
  __shared__ unsigned short rowp_l[NPG + 1];
  __shared__ float pooled_l[10 * CC];
  __shared__ float fch[50];

  int g = blockIdx.x, tid = threadIdx.x;
  int nb = g * NPG;
  int ebase = rowp[nb];
  for (int i = tid; i <= NPG; i += 512) rowp_l[i] = (unsigned short)(rowp[nb + i] - ebase);
  for (int e = tid; e < EPG; e += 512) {
    srcs_l[e] = (unsigned short)(srcs[ebase + e] - nb);
    ew_l[e] = ew[ebase + e];
  }
  for (int i = tid; i < NPG * CC; i += 512) {
    int n = i / CC, c = i - n * CC;
    h_l[n * HP + c] = h_in[(size_t)nb * CC + i];
  }
  __syncthreads();
  norm_pool(h_l, pooled_l, 0, tid);
  __syncthreads();

  bool act = tid < NPG;
  int n = tid;
  float hr[CC], acc[CC];
  for (int l = 0; l < NUM_GC; l++) {
    const float* Wn = wnbr + l * CC * CC;   // uniform-indexed -> scalar loads
    const float* Wr = wroot + l * CC * CC;
    const float* bs = gcb + l * CC;
    if (act) {
#pragma unroll
      for (int c = 0; c < CC; c++) { hr[c] = h_l[n * HP + c]; acc[c] = 0.f; }
#pragma unroll
      for (int k = 0; k < CC; k++) {
        float hk = hr[k];
#pragma unroll
        for (int c = 0; c < CC; c++) acc[c] = fmaf(hk, Wn[k * CC + c], acc[c]);
      }
#pragma unroll
      for (int c = 0; c < CC; c++) hw_l[n * HP + c] = acc[c];
    }
    __syncthreads();
    if (act) {
#pragma unroll
      for (int c = 0; c < CC; c++) acc[c] = bs[c];
#pragma unroll
      for (int k = 0; k < CC; k++) {
        float hk = hr[k];
#pragma unroll
        for (int c = 0; c < CC; c++) acc[c] = fmaf(hk, Wr[k * CC + c], acc[c]);
      }
      int b = rowp_l[n], e = rowp_l[n + 1];
      for (int p = b; p < e; p++) {
        float w = ew_l[p];
        int sbase = (int)srcs_l[p] * HP;
#pragma unroll
        for (int c = 0; c < CC; c++) acc[c] = fmaf(w, hw_l[sbase + c], acc[c]);
      }
#pragma unroll
      for (int c = 0; c < CC; c++) h_l[n * HP + c] = acc[c];
    }
    __syncthreads();
    norm_pool(h_l, pooled_l, l + 1, tid);
    __syncthreads();
  }

  // final MLP
  if (tid < 50) {
    float a = fc1b[tid];
    for (int i = 0; i < 10 * CC; i++) a += pooled_l[i] * fc1w[i * 50 + tid];
    fch[tid] = fmaxf(a, 0.f);
  }
  __syncthreads();
  if (tid < 2) {
    float o = fc2b[tid];
#pragma unroll
    for (int j = 0; j < 50; j++) o += fch[j] * fc2w[j * 2 + tid];
    out[g * 2 + tid] = o;
  }
}

extern "C" void kernel_launch(void* const* d_in, const int* in_sizes, int n_in,
                              void* d_out, int out_size, void* d_ws, size_t ws_size,
                              hipStream_t stream) {
  const float* x     = (const float*)d_in[0];
  const int*   ei    = (const int*)d_in[1];
  const int*   esrc  = ei;
  const int*   edst  = ei + EE;
  const float* eattr = (const float*)d_in[2];
  const float* egw   = (const float*)d_in[4];
  const float* att_s = (const float*)d_in[5];
  const float* att_d = (const float*)d_in[6];
  const float* att_e = (const float*)d_in[7];
  const float* wroot = (const float*)d_in[8];
  const float* wnbr  = (const float*)d_in[9];
  const float* gcb   = (const float*)d_in[10];
  const float* fc1w  = (const float*)d_in[11];
  const float* fc1b  = (const float*)d_in[12];
  const float* fc2w  = (const float*)d_in[13];
  const float* fc2b  = (const float*)d_in[14];
  float* out = (float*)d_out;

  char* ws = (char*)d_ws;
  size_t off = 0;
  auto alloc = [&](size_t bytes) -> void* {
    void* p = ws + off;
    off += (bytes + 255) & ~(size_t)255;
    return p;
  };
  float* xp      = (float*)alloc((size_t)NN * HH * CC * 4);
  float* ssrc    = (float*)alloc((size_t)NN * 8 * 4);
  float* sdst    = (float*)alloc((size_t)NN * 8 * 4);
  float* h       = (float*)alloc((size_t)NN * CC * 4);
  float* ew      = (float*)alloc((size_t)EE * 4);
  float* eattr_p = (float*)alloc((size_t)EE * 4);
  int*   deg     = (int*)alloc((size_t)NN * 4);
  int*   rowp    = (int*)alloc((size_t)(NN + 1) * 4);
  int*   cursor  = (int*)alloc((size_t)NN * 4);
  int*   srcs    = (int*)alloc((size_t)EE * 4);

  // CSR build
  hipMemsetAsync(deg, 0, (size_t)NN * 4, stream);
  k_hist<<<(EE + 255) / 256, 256, 0, stream>>>(edst, deg);
  k_scan<<<1, 1024, 0, stream>>>(deg, rowp);
  hipMemsetAsync(cursor, 0, (size_t)NN * 4, stream);
  k_scatter<<<(EE + 255) / 256, 256, 0, stream>>>(esrc, edst, eattr, rowp, cursor, srcs, eattr_p);

  // EGAT
  k_xp<<<(NN * HH + 255) / 256, 256, 0, stream>>>(x, egw, att_s, att_d, xp, ssrc, sdst);
  k_egat<<<NN, 64, 0, stream>>>(rowp, srcs, eattr_p, ssrc, sdst, att_e, xp, ew, h);

  // fused GC stack + norms + pool + MLP
  k_gcall<<<GN, 512, 0, stream>>>(rowp, srcs, ew, h, wnbr, wroot, gcb,
                                  fc1w, fc1b, fc2w, fc2b, out);
}